// Round 17
// baseline (168.121 us; speedup 1.0000x reference)
//
#include <hip/hip_runtime.h>
#include <hip/hip_fp16.h>

#define SLOPE_ATT 0.2f
#define SLOPE_ACT 0.01f

#define SB 256        // edge-range blocks for count/scatter
#define NBUKMAX 512   // max coarse buckets (dst>>7, N<=65536)

typedef _Float16 hf8 __attribute__((ext_vector_type(8)));
typedef float f32x4 __attribute__((ext_vector_type(4)));

// ---------------------------------------------------------------------------
// MFMA fp16 GEMM body: h[M][128] = A[M][K] @ B[K][128], BT[128][K] fp16.
template<int K, int H, bool A_FP32>
__device__ __forceinline__
void gemm_mfma_body(int gbid, int tid,
                    const void* __restrict__ Av, const _Float16* __restrict__ BT,
                    const float* __restrict__ att_s, const float* __restrict__ att_d,
                    _Float16* __restrict__ hout, float* __restrict__ a_src,
                    float* __restrict__ a_dst, int M)
{
  const int lane = tid & 63;
  const int wid  = tid >> 6;
  const int li   = lane & 15;
  const int lk   = lane >> 4;
  const int rowbase = gbid * 128 + wid * 32;

  const float*    Af = (const float*)Av;
  const _Float16* Ah = (const _Float16*)Av;

  f32x4 acc[2][8];
#pragma unroll
  for (int i = 0; i < 2; ++i)
#pragma unroll
    for (int j = 0; j < 8; ++j) acc[i][j] = (f32x4){0.f, 0.f, 0.f, 0.f};

  const int r0 = min(rowbase + li,      M - 1);
  const int r1 = min(rowbase + 16 + li, M - 1);

#pragma unroll
  for (int ks = 0; ks < K / 32; ++ks) {
    const int kb = ks * 32 + lk * 8;
    hf8 a0, a1;
    if constexpr (A_FP32) {
      const float* p0 = &Af[(size_t)r0 * K + kb];
      const float* p1 = &Af[(size_t)r1 * K + kb];
      float4 x0a = *(const float4*)p0, x0b = *(const float4*)(p0 + 4);
      float4 x1a = *(const float4*)p1, x1b = *(const float4*)(p1 + 4);
      a0[0]=(_Float16)x0a.x; a0[1]=(_Float16)x0a.y; a0[2]=(_Float16)x0a.z; a0[3]=(_Float16)x0a.w;
      a0[4]=(_Float16)x0b.x; a0[5]=(_Float16)x0b.y; a0[6]=(_Float16)x0b.z; a0[7]=(_Float16)x0b.w;
      a1[0]=(_Float16)x1a.x; a1[1]=(_Float16)x1a.y; a1[2]=(_Float16)x1a.z; a1[3]=(_Float16)x1a.w;
      a1[4]=(_Float16)x1b.x; a1[5]=(_Float16)x1b.y; a1[6]=(_Float16)x1b.z; a1[7]=(_Float16)x1b.w;
    } else {
      a0 = *(const hf8*)&Ah[(size_t)r0 * K + kb];
      a1 = *(const hf8*)&Ah[(size_t)r1 * K + kb];
    }
#pragma unroll
    for (int cf = 0; cf < 8; ++cf) {
      hf8 b = *(const hf8*)&BT[(size_t)(cf * 16 + li) * K + kb];
      acc[0][cf] = __builtin_amdgcn_mfma_f32_16x16x32_f16(a0, b, acc[0][cf], 0, 0, 0);
      acc[1][cf] = __builtin_amdgcn_mfma_f32_16x16x32_f16(a1, b, acc[1][cf], 0, 0, 0);
    }
  }

  float sA[8], dA[8];
#pragma unroll
  for (int cf = 0; cf < 8; ++cf) {
    sA[cf] = att_s[cf * 16 + li];
    dA[cf] = att_d[cf * 16 + li];
  }

  const bool full = (rowbase + 32) <= M;
#pragma unroll
  for (int rf = 0; rf < 2; ++rf) {
    const int rb = rowbase + rf * 16 + lk * 4;
#pragma unroll
    for (int reg = 0; reg < 4; ++reg) {
      const int r = rb + reg;
      if (full || r < M) {
#pragma unroll
        for (int cf = 0; cf < 8; ++cf)
          hout[(size_t)r * 128 + cf * 16 + li] = (_Float16)acc[rf][cf][reg];
      }
    }
    if constexpr (H == 4) {
#pragma unroll
      for (int hh = 0; hh < 4; ++hh) {
#pragma unroll
        for (int reg = 0; reg < 4; ++reg) {
          float sp = acc[rf][2*hh][reg] * sA[2*hh] + acc[rf][2*hh+1][reg] * sA[2*hh+1];
          float dp = acc[rf][2*hh][reg] * dA[2*hh] + acc[rf][2*hh+1][reg] * dA[2*hh+1];
          sp += __shfl_xor(sp, 1); sp += __shfl_xor(sp, 2);
          sp += __shfl_xor(sp, 4); sp += __shfl_xor(sp, 8);
          dp += __shfl_xor(dp, 1); dp += __shfl_xor(dp, 2);
          dp += __shfl_xor(dp, 4); dp += __shfl_xor(dp, 8);
          const int r = rb + reg;
          if (li == 0 && r < M) {
            a_src[(size_t)r * 4 + hh] = sp;
            a_dst[(size_t)r * 4 + hh] = dp;
          }
        }
      }
    } else {
#pragma unroll
      for (int reg = 0; reg < 4; ++reg) {
        float sp = 0.f, dp = 0.f;
#pragma unroll
        for (int cf = 0; cf < 8; ++cf) {
          sp += acc[rf][cf][reg] * sA[cf];
          dp += acc[rf][cf][reg] * dA[cf];
        }
        sp += __shfl_xor(sp, 1); sp += __shfl_xor(sp, 2);
        sp += __shfl_xor(sp, 4); sp += __shfl_xor(sp, 8);
        dp += __shfl_xor(dp, 1); dp += __shfl_xor(dp, 2);
        dp += __shfl_xor(dp, 4); dp += __shfl_xor(dp, 8);
        const int r = rb + reg;
        if (li == 0 && r < M) { a_src[r] = sp; a_dst[r] = dp; }
      }
    }
  }
}

// ---------------------------------------------------------------------------
// Dispatch 1: coarse bucket count || convW1 || convW2 || sd32 pack.
__global__ __launch_bounds__(256)
void pre_kernel(const int* __restrict__ ei, int E, int N, int nbuk, int epb1,
                unsigned* __restrict__ cntA, unsigned* __restrict__ sd32,
                const float* __restrict__ W1, _Float16* __restrict__ W1T,
                const float* __restrict__ W2, _Float16* __restrict__ W2T)
{
  __shared__ unsigned hist[NBUKMAX];
  const int bid = blockIdx.x;
  const int tid = threadIdx.x;
  if (bid < SB) {
    for (int j = tid; j < NBUKMAX; j += 256) hist[j] = 0;
    __syncthreads();
    const int EE = E + N;
    const int lo = bid * epb1, hi = min(lo + epb1, EE);
    for (int i = lo + tid; i < hi; i += 256) {
      int d = (i < E) ? ei[E + i] : (i - E);
      atomicAdd(&hist[d >> 7], 1u);
    }
    __syncthreads();
    for (int j = tid; j < nbuk; j += 256)
      cntA[(size_t)bid * NBUKMAX + j] = hist[j];
  } else if (bid < SB + 128) {          // W1: 256x128
    int idx = (bid - SB) * 256 + tid;
    int k = idx >> 7, c = idx & 127;
    W1T[(size_t)c * 256 + k] = (_Float16)W1[idx];
  } else if (bid < SB + 192) {          // W2: 128x128
    int idx = (bid - SB - 128) * 256 + tid;
    int k = idx >> 7, c = idx & 127;
    W2T[(size_t)c * 128 + k] = (_Float16)W2[idx];
  } else {                              // sd32 pack
    const int i = (bid - SB - 192) * 256 + tid;
    const int EE = E + N;
    if (i < EE) {
      unsigned s, d;
      if (i < E) { s = (unsigned)ei[i]; d = (unsigned)ei[E + i]; }
      else       { s = d = (unsigned)(i - E); }
      sd32[i] = (s << 16) | d;
    }
  }
}

// Dispatch 2: per-bucket column scan of cntA -> blkoff (exclusive), buktotal.
__global__ __launch_bounds__(256)
void bukoff_kernel(const unsigned* __restrict__ cntA, unsigned* __restrict__ blkoff,
                   unsigned* __restrict__ buktotal)
{
  __shared__ unsigned s[256];
  const int j = blockIdx.x;
  const int t = threadIdx.x;
  unsigned v0 = cntA[(size_t)t * NBUKMAX + j];
  s[t] = v0;
  __syncthreads();
  for (int off = 1; off < 256; off <<= 1) {
    unsigned v = (t >= off) ? s[t - off] : 0u;
    __syncthreads();
    s[t] += v;
    __syncthreads();
  }
  blkoff[(size_t)t * NBUKMAX + j] = s[t] - v0;
  if (t == 255) buktotal[j] = s[255];
}

// Inline exclusive scan of buktotal[0..nbuk) -> bs[0..nbuk).
__device__ __forceinline__
void bukstart_scan(const unsigned* __restrict__ buktotal, int nbuk,
                   unsigned* bt, unsigned* ps, unsigned* bs, int tid)
{
  for (int j = tid; j < NBUKMAX; j += 256) bt[j] = (j < nbuk) ? buktotal[j] : 0u;
  __syncthreads();
  unsigned pair = bt[2 * tid] + bt[2 * tid + 1];
  ps[tid] = pair;
  __syncthreads();
  for (int off = 1; off < 256; off <<= 1) {
    unsigned v = (tid >= off) ? ps[tid - off] : 0u;
    __syncthreads();
    ps[tid] += v;
    __syncthreads();
  }
  unsigned e0 = ps[tid] - pair;
  bs[2 * tid]     = e0;
  bs[2 * tid + 1] = e0 + bt[2 * tid];
  __syncthreads();
}

// Dispatch 3: gemm layer-1 || bucket scatter (edges -> ebuk grouped by bucket).
__global__ __launch_bounds__(256)
void gemm1_scatter_kernel(int E, int N, int nbuk, int epb1,
                          const unsigned* __restrict__ sd32,
                          const unsigned* __restrict__ blkoff,
                          const unsigned* __restrict__ buktotal,
                          unsigned* __restrict__ ebuk,
                          const float* __restrict__ x, const _Float16* __restrict__ W1T,
                          const float* __restrict__ as1, const float* __restrict__ ad1,
                          _Float16* __restrict__ h, float* __restrict__ asv,
                          float* __restrict__ adv, int ggrid)
{
  __shared__ unsigned bt[NBUKMAX], bs[NBUKMAX], cur[NBUKMAX];
  __shared__ unsigned ps[256];
  const int bid = blockIdx.x;
  const int tid = threadIdx.x;
  if (bid < ggrid) {
    gemm_mfma_body<256, 4, true>(bid, tid, x, W1T, as1, ad1, h, asv, adv, N);
  } else {
    const int sb = bid - ggrid;
    bukstart_scan(buktotal, nbuk, bt, ps, bs, tid);
    for (int j = tid; j < nbuk; j += 256)
      cur[j] = bs[j] + blkoff[(size_t)sb * NBUKMAX + j];
    __syncthreads();
    const int EE = E + N;
    const int lo = sb * epb1, hi = min(lo + epb1, EE);
    for (int i = lo + tid; i < hi; i += 256) {
      unsigned sd = sd32[i];
      unsigned buk = (sd & 0xFFFFu) >> 7;
      unsigned slot = atomicAdd(&cur[buk], 1u);
      ebuk[slot] = sd;
    }
  }
}

// Dispatch 4: per-bucket CSR build + layer-1 alpha (pre-normalized fp16).
__global__ __launch_bounds__(256)
void csr_build_kernel(int N, int nbuk,
                      const unsigned* __restrict__ buktotal,
                      const unsigned* __restrict__ ebuk,
                      const float* __restrict__ asv, const float* __restrict__ adv,
                      unsigned* __restrict__ deg, unsigned* __restrict__ row_start,
                      unsigned short* __restrict__ csr16,
                      __half* __restrict__ alf1)
{
  __shared__ unsigned bt[NBUKMAX], bs[NBUKMAX];
  __shared__ unsigned ps[256];
  __shared__ unsigned hist[128], hs[128], cur2[128], rsl[128];
  const int j = blockIdx.x;
  const int tid = threadIdx.x;

  bukstart_scan(buktotal, nbuk, bt, ps, bs, tid);
  const unsigned estart = bs[j];
  const unsigned ecount = bt[j];
  const int n0 = j * 128;

  if (tid < 128) hist[tid] = 0;
  __syncthreads();
  for (unsigned i = estart + tid; i < estart + ecount; i += 256)
    atomicAdd(&hist[ebuk[i] & 127u], 1u);
  __syncthreads();
  unsigned hv = (tid < 128) ? hist[tid] : 0u;
  if (tid < 128) hs[tid] = hv;
  __syncthreads();
  for (int off = 1; off < 128; off <<= 1) {
    unsigned v = 0;
    if (tid < 128 && tid >= off) v = hs[tid - off];
    __syncthreads();
    if (tid < 128) hs[tid] += v;
    __syncthreads();
  }
  if (tid < 128) {
    unsigned excl = hs[tid] - hv;
    cur2[tid] = estart + excl;
    rsl[tid]  = estart + excl;
    if (n0 + tid < N) {
      deg[n0 + tid] = hv;
      row_start[n0 + tid] = estart + excl;
    }
  }
  __syncthreads();
  for (unsigned i = estart + tid; i < estart + ecount; i += 256) {
    unsigned sd = ebuk[i];
    unsigned slot = atomicAdd(&cur2[sd & 127u], 1u);
    csr16[slot] = (unsigned short)(sd >> 16);
  }
  __syncthreads();   // csr16 visible block-wide

  // ---- layer-1 alpha: 2 threads per dst, serial over its csr range ----
  const int dloc = tid >> 1;
  const int par  = tid & 1;
  const int n = n0 + dloc;
  if (n < N) {
    const unsigned rs = rsl[dloc];
    const unsigned dg = hist[dloc];
    float4 dv = ((const float4*)adv)[n];
    float zx = 0.f, zy = 0.f, zz = 0.f, zw = 0.f;
    for (unsigned i = par; i < dg; i += 2) {
      unsigned pos = rs + i;
      unsigned s = csr16[pos];
      float4 av = ((const float4*)asv)[s];
      float e0 = av.x + dv.x; e0 = (e0 >= 0.f) ? e0 : SLOPE_ATT * e0;
      float e1 = av.y + dv.y; e1 = (e1 >= 0.f) ? e1 : SLOPE_ATT * e1;
      float e2 = av.z + dv.z; e2 = (e2 >= 0.f) ? e2 : SLOPE_ATT * e2;
      float e3 = av.w + dv.w; e3 = (e3 >= 0.f) ? e3 : SLOPE_ATT * e3;
      float w0 = __expf(e0 - 4.f), w1 = __expf(e1 - 4.f);
      float w2 = __expf(e2 - 4.f), w3 = __expf(e3 - 4.f);
      zx += w0; zy += w1; zz += w2; zw += w3;
      union { __half2 q[2]; ushort4 u; } uu;
      uu.q[0] = __floats2half2_rn(w0, w1);
      uu.q[1] = __floats2half2_rn(w2, w3);
      *(ushort4*)&alf1[(size_t)pos * 4] = uu.u;
    }
    zx += __shfl_xor(zx, 1); zy += __shfl_xor(zy, 1);
    zz += __shfl_xor(zz, 1); zw += __shfl_xor(zw, 1);
    const float ix = 1.f / (zx + 1e-16f), iy = 1.f / (zy + 1e-16f);
    const float iz = 1.f / (zz + 1e-16f), iw = 1.f / (zw + 1e-16f);
    for (unsigned i = par; i < dg; i += 2) {
      unsigned pos = rs + i;
      union { ushort4 u; __half2 q[2]; } vv;
      vv.u = *(const ushort4*)&alf1[(size_t)pos * 4];
      float2 f0 = __half22float2(vv.q[0]);
      float2 f1 = __half22float2(vv.q[1]);
      union { __half2 q[2]; ushort4 u; } ww;
      ww.q[0] = __floats2half2_rn(f0.x * ix, f0.y * iy);
      ww.q[1] = __floats2half2_rn(f1.x * iz, f1.y * iw);
      *(ushort4*)&alf1[(size_t)pos * 4] = ww.u;
    }
  }
}

// Dispatch 6: layer-2 alpha (after asv2/adv2 exist). One block per bucket.
__global__ __launch_bounds__(256)
void alpha2_kernel(int N,
                   const unsigned* __restrict__ row_start,
                   const unsigned* __restrict__ deg,
                   const unsigned short* __restrict__ csr16,
                   const float* __restrict__ asv2, const float* __restrict__ adv2,
                   __half* __restrict__ alf2)
{
  const int tid = threadIdx.x;
  const int dloc = tid >> 1;
  const int par  = tid & 1;
  const int n = blockIdx.x * 128 + dloc;
  if (n >= N) return;
  const unsigned rs = row_start[n];
  const unsigned dg = deg[n];
  const float dv = adv2[n];
  float z = 0.f;
  for (unsigned i = par; i < dg; i += 2) {
    unsigned pos = rs + i;
    unsigned s = csr16[pos];
    float e = asv2[s] + dv;
    e = (e >= 0.f) ? e : SLOPE_ATT * e;
    float w = __expf(e - 4.f);
    z += w;
    alf2[pos] = __float2half(w);
  }
  z += __shfl_xor(z, 1);
  const float izv = 1.f / (z + 1e-16f);
  for (unsigned i = par; i < dg; i += 2) {
    unsigned pos = rs + i;
    alf2[pos] = __float2half(__half2float(alf2[pos]) * izv);
  }
}

// ---------------------------------------------------------------------------
// Dispatch 5: FUSED slim-aggregate layer-1 + gemm layer-2 + layer-2 att dots.
__global__ __launch_bounds__(256)
void agg1_gemm2_kernel(const unsigned* __restrict__ row_start,
                       const unsigned* __restrict__ deg,
                       const unsigned short* __restrict__ csr16,
                       const __half* __restrict__ alf1,
                       const __half* __restrict__ h,
                       const float* __restrict__ bias,
                       const _Float16* __restrict__ W2T,
                       const float* __restrict__ as2, const float* __restrict__ ad2,
                       _Float16* __restrict__ h2,
                       float* __restrict__ asv2, float* __restrict__ adv2, int N)
{
  __shared__ _Float16 actS[16][132];
  __shared__ float sdots[2][16];

  const int lane = threadIdx.x & 63;
  const int wid  = threadIdx.x >> 6;
  const int l5   = lane & 15;
  const int nl   = wid * 4 + (lane >> 4);
  const int nb   = blockIdx.x * 16;
  const int n    = nb + nl;
  const int nn   = min(n, N - 1);
  const int hd   = l5 >> 2;

  // phase 1: slim aggregate (H=4): acc += alpha * h[src]
  const unsigned beg = row_start[nn];
  const unsigned cnt = deg[nn];
  unsigned cmax = cnt;
  cmax = max(cmax, (unsigned)__shfl_xor((int)cmax, 16));
  cmax = max(cmax, (unsigned)__shfl_xor((int)cmax, 32));

  const float4* __restrict__ h4 = (const float4*)h;

  float acc[8];
#pragma unroll
  for (int j = 0; j < 8; ++j) acc[j] = 0.f;

  unsigned i = 0;
  for (; i + 4 <= cmax; i += 4) {
    unsigned p0 = beg + min(i,     cnt - 1);
    unsigned p1 = beg + min(i + 1, cnt - 1);
    unsigned p2 = beg + min(i + 2, cnt - 1);
    unsigned p3 = beg + min(i + 3, cnt - 1);
    unsigned s0 = csr16[p0], s1 = csr16[p1], s2 = csr16[p2], s3 = csr16[p3];
    float w0 = __half2float(alf1[(size_t)p0 * 4 + hd]);
    float w1 = __half2float(alf1[(size_t)p1 * 4 + hd]);
    float w2 = __half2float(alf1[(size_t)p2 * 4 + hd]);
    float w3 = __half2float(alf1[(size_t)p3 * 4 + hd]);
    float4 v0 = h4[(size_t)s0 * 16 + l5];
    float4 v1 = h4[(size_t)s1 * 16 + l5];
    float4 v2 = h4[(size_t)s2 * 16 + l5];
    float4 v3 = h4[(size_t)s3 * 16 + l5];
    w0 = (i     < cnt) ? w0 : 0.f;
    w1 = (i + 1 < cnt) ? w1 : 0.f;
    w2 = (i + 2 < cnt) ? w2 : 0.f;
    w3 = (i + 3 < cnt) ? w3 : 0.f;
    const __half2* q0 = (const __half2*)&v0;
    const __half2* q1 = (const __half2*)&v1;
    const __half2* q2 = (const __half2*)&v2;
    const __half2* q3 = (const __half2*)&v3;
#pragma unroll
    for (int j = 0; j < 4; ++j) {
      float2 f0 = __half22float2(q0[j]);
      float2 f1 = __half22float2(q1[j]);
      float2 f2 = __half22float2(q2[j]);
      float2 f3 = __half22float2(q3[j]);
      acc[2*j]   += w0 * f0.x + w1 * f1.x + w2 * f2.x + w3 * f3.x;
      acc[2*j+1] += w0 * f0.y + w1 * f1.y + w2 * f2.y + w3 * f3.y;
    }
  }
  for (; i < cmax; ++i) {
    unsigned p0 = beg + min(i, cnt - 1);
    unsigned s0 = csr16[p0];
    float w0 = __half2float(alf1[(size_t)p0 * 4 + hd]);
    float4 v0 = h4[(size_t)s0 * 16 + l5];
    w0 = (i < cnt) ? w0 : 0.f;
    const __half2* q0 = (const __half2*)&v0;
#pragma unroll
    for (int j = 0; j < 4; ++j) {
      float2 f0 = __half22float2(q0[j]);
      acc[2*j]   += w0 * f0.x;
      acc[2*j+1] += w0 * f0.y;
    }
  }

  float4 b0 = ((const float4*)bias)[l5 * 2];
  float4 b1 = ((const float4*)bias)[l5 * 2 + 1];
  float o[8];
  o[0] = acc[0] + b0.x;  o[1] = acc[1] + b0.y;
  o[2] = acc[2] + b0.z;  o[3] = acc[3] + b0.w;
  o[4] = acc[4] + b1.x;  o[5] = acc[5] + b1.y;
  o[6] = acc[6] + b1.z;  o[7] = acc[7] + b1.w;
#pragma unroll
  for (int j = 0; j < 8; ++j) o[j] = (o[j] >= 0.f) ? o[j] : SLOPE_ACT * o[j];

  // phase 2: stage act1
#pragma unroll
  for (int j = 0; j < 8; ++j) actS[nl][l5 * 8 + j] = (_Float16)o[j];
  if (threadIdx.x < 32) sdots[threadIdx.x >> 4][threadIdx.x & 15] = 0.f;
  __syncthreads();

  // phase 3: mini-GEMM h2 = act1 @ W2 + H=1 dots
  const int li = l5;
  const int lk = lane >> 4;
#pragma unroll
  for (int t = 0; t < 2; ++t) {
    const int c0 = wid * 32 + t * 16;
    f32x4 a2 = (f32x4){0.f, 0.f, 0.f, 0.f};
#pragma unroll
    for (int ks = 0; ks < 4; ++ks) {
      hf8 af = *(const hf8*)&actS[li][ks * 32 + lk * 8];
      hf8 bf = *(const hf8*)&W2T[(size_t)(c0 + li) * 128 + ks * 32 + lk * 8];
      a2 = __builtin_amdgcn_mfma_f32_16x16x32_f16(af, bf, a2, 0, 0, 0);
    }
    const float asc = as2[c0 + li];
    const float adc = ad2[c0 + li];
#pragma unroll
    for (int reg = 0; reg < 4; ++reg) {
      const int r = lk * 4 + reg;
      float hv = a2[reg];
      if (nb + r < N) h2[(size_t)(nb + r) * 128 + c0 + li] = (_Float16)hv;
      float sp = hv * asc;
      float dp = hv * adc;
      sp += __shfl_xor(sp, 1); sp += __shfl_xor(sp, 2);
      sp += __shfl_xor(sp, 4); sp += __shfl_xor(sp, 8);
      dp += __shfl_xor(dp, 1); dp += __shfl_xor(dp, 2);
      dp += __shfl_xor(dp, 4); dp += __shfl_xor(dp, 8);
      if (li == 0) {
        atomicAdd(&sdots[0][r], sp);
        atomicAdd(&sdots[1][r], dp);
      }
    }
  }
  __syncthreads();
  if (threadIdx.x < 16) {
    const int r = threadIdx.x;
    if (nb + r < N) {
      asv2[nb + r] = sdots[0][r];
      adv2[nb + r] = sdots[1][r];
    }
  }
}

// ---------------------------------------------------------------------------
// Dispatch 7: slim aggregate layer-2 (H=1, fp32 out) -> d_out.
__global__ __launch_bounds__(256)
void aggregate2_kernel(const unsigned* __restrict__ row_start,
                       const unsigned* __restrict__ deg,
                       const unsigned short* __restrict__ csr16,
                       const __half* __restrict__ alf2,
                       const __half* __restrict__ h,
                       const float* __restrict__ bias,
                       float* __restrict__ out, int N)
{
  const int lane = threadIdx.x & 63;
  const int wid  = threadIdx.x >> 6;
  const int l5   = lane & 15;
  const int n    = blockIdx.x * 16 + wid * 4 + (lane >> 4);
  const int nn   = min(n, N - 1);

  const unsigned beg = row_start[nn];
  const unsigned cnt = deg[nn];
  unsigned cmax = cnt;
  cmax = max(cmax, (unsigned)__shfl_xor((int)cmax, 16));
  cmax = max(cmax, (unsigned)__shfl_xor((int)cmax, 32));

  const float4* __restrict__ h4 = (const float4*)h;

  float acc[8];
#pragma unroll
  for (int j = 0; j < 8; ++j) acc[j] = 0.f;

  unsigned i = 0;
  for (; i + 4 <= cmax; i += 4) {
    unsigned p0 = beg + min(i,     cnt - 1);
    unsigned p1 = beg + min(i + 1, cnt - 1);
    unsigned p2 = beg + min(i + 2, cnt - 1);
    unsigned p3 = beg + min(i + 3, cnt - 1);
    unsigned s0 = csr16[p0], s1 = csr16[p1], s2 = csr16[p2], s3 = csr16[p3];
    float w0 = __half2float(alf2[p0]);
    float w1 = __half2float(alf2[p1]);
    float w2 = __half2float(alf2[p2]);
    float w3 = __half2float(alf2[p3]);
    float4 v0 = h4[(size_t)s0 * 16 + l5];
    float4 v1 = h4[(size_t)s1 * 16 + l5];
    float4 v2 = h4[(size_t)s2 * 16 + l5];
    float4 v3 = h4[(size_t)s3 * 16 + l5];
    w0 = (i     < cnt) ? w0 : 0.f;
    w1 = (i + 1 < cnt) ? w1 : 0.f;
    w2 = (i + 2 < cnt) ? w2 : 0.f;
    w3 = (i + 3 < cnt) ? w3 : 0.f;
    const __half2* q0 = (const __half2*)&v0;
    const __half2* q1 = (const __half2*)&v1;
    const __half2* q2 = (const __half2*)&v2;
    const __half2* q3 = (const __half2*)&v3;
#pragma unroll
    for (int j = 0; j < 4; ++j) {
      float2 f0 = __half22float2(q0[j]);
      float2 f1 = __half22float2(q1[j]);
      float2 f2 = __half22float2(q2[j]);
      float2 f3 = __half22float2(q3[j]);
      acc[2*j]   += w0 * f0.x + w1 * f1.x + w2 * f2.x + w3 * f3.x;
      acc[2*j+1] += w0 * f0.y + w1 * f1.y + w2 * f2.y + w3 * f3.y;
    }
  }
  for (; i < cmax; ++i) {
    unsigned p0 = beg + min(i, cnt - 1);
    unsigned s0 = csr16[p0];
    float w0 = __half2float(alf2[p0]);
    float4 v0 = h4[(size_t)s0 * 16 + l5];
    w0 = (i < cnt) ? w0 : 0.f;
    const __half2* q0 = (const __half2*)&v0;
#pragma unroll
    for (int j = 0; j < 4; ++j) {
      float2 f0 = __half22float2(q0[j]);
      acc[2*j]   += w0 * f0.x;
      acc[2*j+1] += w0 * f0.y;
    }
  }

  float4 b0 = ((const float4*)bias)[l5 * 2];
  float4 b1 = ((const float4*)bias)[l5 * 2 + 1];
  float o[8];
  o[0] = acc[0] + b0.x;  o[1] = acc[1] + b0.y;
  o[2] = acc[2] + b0.z;  o[3] = acc[3] + b0.w;
  o[4] = acc[4] + b1.x;  o[5] = acc[5] + b1.y;
  o[6] = acc[6] + b1.z;  o[7] = acc[7] + b1.w;
#pragma unroll
  for (int j = 0; j < 8; ++j) o[j] = (o[j] >= 0.f) ? o[j] : SLOPE_ACT * o[j];

  if (n < N) {
    ((float4*)out)[(size_t)n * 32 + l5 * 2]     = make_float4(o[0], o[1], o[2], o[3]);
    ((float4*)out)[(size_t)n * 32 + l5 * 2 + 1] = make_float4(o[4], o[5], o[6], o[7]);
  }
}

// ---------------------------------------------------------------------------
extern "C" void kernel_launch(void* const* d_in, const int* in_sizes, int n_in,
                              void* d_out, int out_size, void* d_ws, size_t ws_size,
                              hipStream_t stream)
{
  const float* x   = (const float*)d_in[0];
  const int*   ei  = (const int*)d_in[1];
  const float* W1  = (const float*)d_in[2];
  const float* as1 = (const float*)d_in[3];
  const float* ad1 = (const float*)d_in[4];
  const float* b1  = (const float*)d_in[5];
  const float* W2  = (const float*)d_in[6];
  const float* as2 = (const float*)d_in[7];
  const float* ad2 = (const float*)d_in[8];
  const float* b2  = (const float*)d_in[9];
  float* out = (float*)d_out;

  const int N  = in_sizes[0] / 256;
  const int E  = in_sizes[1] / 2;
  const int EE = E + N;
  const int nbuk = (N + 127) / 128;            // <= 512 for N <= 65536
  const int epb1 = (EE + SB - 1) / SB;         // edges per count/scatter block
  const int pgrid = (EE + 255) / 256;          // packing blocks

  float* ws = (float*)d_ws;
  size_t o = 0;
  _Float16* h    = (_Float16*)(ws + o); o += (size_t)N * 64;   // layer-1 h [N][128] fp16
  _Float16* h2   = (_Float16*)(ws + o); o += (size_t)N * 64;   // layer-2 h [N][128] fp16
  float* asv  = ws + o; o += (size_t)N * 4;                    // layer-1 dots (H=4)
  float* adv  = ws + o; o += (size_t)N * 4;
  float* asv2 = ws + o; o += (size_t)N;                        // layer-2 dots (H=1)
  float* adv2 = ws + o; o += (size_t)N;
  _Float16* W1T = (_Float16*)(ws + o); o += 128 * 256 / 2;     // [128][256] fp16
  _Float16* W2T = (_Float16*)(ws + o); o += 128 * 128 / 2;     // [128][128] fp16
  unsigned* deg       = (unsigned*)(ws + o); o += (size_t)N;
  unsigned* row_start = (unsigned*)(ws + o); o += (size_t)N;
  unsigned* cntA      = (unsigned*)(ws + o); o += (size_t)SB * NBUKMAX;   // 512 KB
  unsigned* blkoff    = (unsigned*)(ws + o); o += (size_t)SB * NBUKMAX;   // 512 KB
  unsigned* buktotal  = (unsigned*)(ws + o); o += NBUKMAX;
  unsigned* sd32      = (unsigned*)(ws + o); o += (size_t)EE;             // 3.4 MB
  unsigned* ebuk      = (unsigned*)(ws + o); o += (size_t)EE;             // 3.4 MB
  unsigned short* csr16 = (unsigned short*)(ws + o); o += (size_t)(EE + 1) / 2; // 1.7 MB
  __half* alf1 = (__half*)(ws + o); o += (size_t)EE * 2;                  // 6.8 MB
  __half* alf2 = (__half*)(ws + o); o += (size_t)(EE + 1) / 2;            // 1.7 MB

  const int ngrid = (N + 15) / 16;
  const int ggrid = (N + 127) / 128;

  // 1) bucket count || convW1 || convW2 || sd32 pack
  pre_kernel<<<SB + 192 + pgrid, 256, 0, stream>>>(
      ei, E, N, nbuk, epb1, cntA, sd32, W1, W1T, W2, W2T);
  // 2) per-bucket column scan
  bukoff_kernel<<<nbuk, 256, 0, stream>>>(cntA, blkoff, buktotal);
  // 3) gemm layer-1 || bucket scatter
  gemm1_scatter_kernel<<<ggrid + SB, 256, 0, stream>>>(
      E, N, nbuk, epb1, sd32, blkoff, buktotal, ebuk,
      x, W1T, as1, ad1, h, asv, adv, ggrid);
  // 4) per-bucket CSR build + layer-1 alpha (pre-normalized fp16)
  csr_build_kernel<<<nbuk, 256, 0, stream>>>(
      N, nbuk, buktotal, ebuk, asv, adv, deg, row_start, csr16, alf1);
  // 5) slim aggregate layer-1 + gemm layer-2 + layer-2 dots (fused)
  agg1_gemm2_kernel<<<ngrid, 256, 0, stream>>>(
      row_start, deg, csr16, alf1, (const __half*)h, b1,
      W2T, as2, ad2, h2, asv2, adv2, N);
  // 6) layer-2 alpha (bucket-local)
  alpha2_kernel<<<nbuk, 256, 0, stream>>>(
      N, row_start, deg, csr16, asv2, adv2, alf2);
  // 7) slim aggregate layer-2 -> out (fp32)
  aggregate2_kernel<<<ngrid, 256, 0, stream>>>(
      row_start, deg, csr16, alf2, (const __half*)h2, b2, out, N);
}

// Round 18
// 142.733 us; speedup vs baseline: 1.1779x; 1.1779x over previous
//
#include <hip/hip_runtime.h>
#include <hip/hip_fp16.h>

#define SLOPE_ATT 0.2f
#define SLOPE_ACT 0.01f

#define SB 256        // edge-range blocks for count/scatter
#define NBUKMAX 512   // max coarse buckets (dst>>7, N<=65536)

typedef _Float16 hf8 __attribute__((ext_vector_type(8)));
typedef float f32x4 __attribute__((ext_vector_type(4)));

// ---------------------------------------------------------------------------
// MFMA fp16 GEMM body: h[M][128] = A[M][K] @ B[K][128], BT[128][K] fp16.
template<int K, int H, bool A_FP32>
__device__ __forceinline__
void gemm_mfma_body(int gbid, int tid,
                    const void* __restrict__ Av, const _Float16* __restrict__ BT,
                    const float* __restrict__ att_s, const float* __restrict__ att_d,
                    _Float16* __restrict__ hout, float* __restrict__ a_src,
                    float* __restrict__ a_dst, int M)
{
  const int lane = tid & 63;
  const int wid  = tid >> 6;
  const int li   = lane & 15;
  const int lk   = lane >> 4;
  const int rowbase = gbid * 128 + wid * 32;

  const float*    Af = (const float*)Av;
  const _Float16* Ah = (const _Float16*)Av;

  f32x4 acc[2][8];
#pragma unroll
  for (int i = 0; i < 2; ++i)
#pragma unroll
    for (int j = 0; j < 8; ++j) acc[i][j] = (f32x4){0.f, 0.f, 0.f, 0.f};

  const int r0 = min(rowbase + li,      M - 1);
  const int r1 = min(rowbase + 16 + li, M - 1);

#pragma unroll
  for (int ks = 0; ks < K / 32; ++ks) {
    const int kb = ks * 32 + lk * 8;
    hf8 a0, a1;
    if constexpr (A_FP32) {
      const float* p0 = &Af[(size_t)r0 * K + kb];
      const float* p1 = &Af[(size_t)r1 * K + kb];
      float4 x0a = *(const float4*)p0, x0b = *(const float4*)(p0 + 4);
      float4 x1a = *(const float4*)p1, x1b = *(const float4*)(p1 + 4);
      a0[0]=(_Float16)x0a.x; a0[1]=(_Float16)x0a.y; a0[2]=(_Float16)x0a.z; a0[3]=(_Float16)x0a.w;
      a0[4]=(_Float16)x0b.x; a0[5]=(_Float16)x0b.y; a0[6]=(_Float16)x0b.z; a0[7]=(_Float16)x0b.w;
      a1[0]=(_Float16)x1a.x; a1[1]=(_Float16)x1a.y; a1[2]=(_Float16)x1a.z; a1[3]=(_Float16)x1a.w;
      a1[4]=(_Float16)x1b.x; a1[5]=(_Float16)x1b.y; a1[6]=(_Float16)x1b.z; a1[7]=(_Float16)x1b.w;
    } else {
      a0 = *(const hf8*)&Ah[(size_t)r0 * K + kb];
      a1 = *(const hf8*)&Ah[(size_t)r1 * K + kb];
    }
#pragma unroll
    for (int cf = 0; cf < 8; ++cf) {
      hf8 b = *(const hf8*)&BT[(size_t)(cf * 16 + li) * K + kb];
      acc[0][cf] = __builtin_amdgcn_mfma_f32_16x16x32_f16(a0, b, acc[0][cf], 0, 0, 0);
      acc[1][cf] = __builtin_amdgcn_mfma_f32_16x16x32_f16(a1, b, acc[1][cf], 0, 0, 0);
    }
  }

  float sA[8], dA[8];
#pragma unroll
  for (int cf = 0; cf < 8; ++cf) {
    sA[cf] = att_s[cf * 16 + li];
    dA[cf] = att_d[cf * 16 + li];
  }

  const bool full = (rowbase + 32) <= M;
#pragma unroll
  for (int rf = 0; rf < 2; ++rf) {
    const int rb = rowbase + rf * 16 + lk * 4;
#pragma unroll
    for (int reg = 0; reg < 4; ++reg) {
      const int r = rb + reg;
      if (full || r < M) {
#pragma unroll
        for (int cf = 0; cf < 8; ++cf)
          hout[(size_t)r * 128 + cf * 16 + li] = (_Float16)acc[rf][cf][reg];
      }
    }
    if constexpr (H == 4) {
#pragma unroll
      for (int hh = 0; hh < 4; ++hh) {
#pragma unroll
        for (int reg = 0; reg < 4; ++reg) {
          float sp = acc[rf][2*hh][reg] * sA[2*hh] + acc[rf][2*hh+1][reg] * sA[2*hh+1];
          float dp = acc[rf][2*hh][reg] * dA[2*hh] + acc[rf][2*hh+1][reg] * dA[2*hh+1];
          sp += __shfl_xor(sp, 1); sp += __shfl_xor(sp, 2);
          sp += __shfl_xor(sp, 4); sp += __shfl_xor(sp, 8);
          dp += __shfl_xor(dp, 1); dp += __shfl_xor(dp, 2);
          dp += __shfl_xor(dp, 4); dp += __shfl_xor(dp, 8);
          const int r = rb + reg;
          if (li == 0 && r < M) {
            a_src[(size_t)r * 4 + hh] = sp;
            a_dst[(size_t)r * 4 + hh] = dp;
          }
        }
      }
    } else {
#pragma unroll
      for (int reg = 0; reg < 4; ++reg) {
        float sp = 0.f, dp = 0.f;
#pragma unroll
        for (int cf = 0; cf < 8; ++cf) {
          sp += acc[rf][cf][reg] * sA[cf];
          dp += acc[rf][cf][reg] * dA[cf];
        }
        sp += __shfl_xor(sp, 1); sp += __shfl_xor(sp, 2);
        sp += __shfl_xor(sp, 4); sp += __shfl_xor(sp, 8);
        dp += __shfl_xor(dp, 1); dp += __shfl_xor(dp, 2);
        dp += __shfl_xor(dp, 4); dp += __shfl_xor(dp, 8);
        const int r = rb + reg;
        if (li == 0 && r < M) { a_src[r] = sp; a_dst[r] = dp; }
      }
    }
  }
}

// ---------------------------------------------------------------------------
// Dispatch 1: coarse bucket count || convW1 || convW2 || sd32 pack.
__global__ __launch_bounds__(256)
void pre_kernel(const int* __restrict__ ei, int E, int N, int nbuk, int epb1,
                unsigned* __restrict__ cntA, unsigned* __restrict__ sd32,
                const float* __restrict__ W1, _Float16* __restrict__ W1T,
                const float* __restrict__ W2, _Float16* __restrict__ W2T)
{
  __shared__ unsigned hist[NBUKMAX];
  const int bid = blockIdx.x;
  const int tid = threadIdx.x;
  if (bid < SB) {
    for (int j = tid; j < NBUKMAX; j += 256) hist[j] = 0;
    __syncthreads();
    const int EE = E + N;
    const int lo = bid * epb1, hi = min(lo + epb1, EE);
    for (int i = lo + tid; i < hi; i += 256) {
      int d = (i < E) ? ei[E + i] : (i - E);
      atomicAdd(&hist[d >> 7], 1u);
    }
    __syncthreads();
    for (int j = tid; j < nbuk; j += 256)
      cntA[(size_t)bid * NBUKMAX + j] = hist[j];
  } else if (bid < SB + 128) {          // W1: 256x128
    int idx = (bid - SB) * 256 + tid;
    int k = idx >> 7, c = idx & 127;
    W1T[(size_t)c * 256 + k] = (_Float16)W1[idx];
  } else if (bid < SB + 192) {          // W2: 128x128
    int idx = (bid - SB - 128) * 256 + tid;
    int k = idx >> 7, c = idx & 127;
    W2T[(size_t)c * 128 + k] = (_Float16)W2[idx];
  } else {                              // sd32 pack
    const int i = (bid - SB - 192) * 256 + tid;
    const int EE = E + N;
    if (i < EE) {
      unsigned s, d;
      if (i < E) { s = (unsigned)ei[i]; d = (unsigned)ei[E + i]; }
      else       { s = d = (unsigned)(i - E); }
      sd32[i] = (s << 16) | d;
    }
  }
}

// Dispatch 2: per-bucket column scan of cntA -> blkoff (exclusive), buktotal.
__global__ __launch_bounds__(256)
void bukoff_kernel(const unsigned* __restrict__ cntA, unsigned* __restrict__ blkoff,
                   unsigned* __restrict__ buktotal)
{
  __shared__ unsigned s[256];
  const int j = blockIdx.x;
  const int t = threadIdx.x;
  unsigned v0 = cntA[(size_t)t * NBUKMAX + j];
  s[t] = v0;
  __syncthreads();
  for (int off = 1; off < 256; off <<= 1) {
    unsigned v = (t >= off) ? s[t - off] : 0u;
    __syncthreads();
    s[t] += v;
    __syncthreads();
  }
  blkoff[(size_t)t * NBUKMAX + j] = s[t] - v0;
  if (t == 255) buktotal[j] = s[255];
}

// Inline exclusive scan of buktotal[0..nbuk) -> bs[0..nbuk).
__device__ __forceinline__
void bukstart_scan(const unsigned* __restrict__ buktotal, int nbuk,
                   unsigned* bt, unsigned* ps, unsigned* bs, int tid)
{
  for (int j = tid; j < NBUKMAX; j += 256) bt[j] = (j < nbuk) ? buktotal[j] : 0u;
  __syncthreads();
  unsigned pair = bt[2 * tid] + bt[2 * tid + 1];
  ps[tid] = pair;
  __syncthreads();
  for (int off = 1; off < 256; off <<= 1) {
    unsigned v = (tid >= off) ? ps[tid - off] : 0u;
    __syncthreads();
    ps[tid] += v;
    __syncthreads();
  }
  unsigned e0 = ps[tid] - pair;
  bs[2 * tid]     = e0;
  bs[2 * tid + 1] = e0 + bt[2 * tid];
  __syncthreads();
}

// Dispatch 3: gemm layer-1 || bucket scatter (edges -> ebuk grouped by bucket).
__global__ __launch_bounds__(256)
void gemm1_scatter_kernel(int E, int N, int nbuk, int epb1,
                          const unsigned* __restrict__ sd32,
                          const unsigned* __restrict__ blkoff,
                          const unsigned* __restrict__ buktotal,
                          unsigned* __restrict__ ebuk,
                          const float* __restrict__ x, const _Float16* __restrict__ W1T,
                          const float* __restrict__ as1, const float* __restrict__ ad1,
                          _Float16* __restrict__ h, float* __restrict__ asv,
                          float* __restrict__ adv, int ggrid)
{
  __shared__ unsigned bt[NBUKMAX], bs[NBUKMAX], cur[NBUKMAX];
  __shared__ unsigned ps[256];
  const int bid = blockIdx.x;
  const int tid = threadIdx.x;
  if (bid < ggrid) {
    gemm_mfma_body<256, 4, true>(bid, tid, x, W1T, as1, ad1, h, asv, adv, N);
  } else {
    const int sb = bid - ggrid;
    bukstart_scan(buktotal, nbuk, bt, ps, bs, tid);
    for (int j = tid; j < nbuk; j += 256)
      cur[j] = bs[j] + blkoff[(size_t)sb * NBUKMAX + j];
    __syncthreads();
    const int EE = E + N;
    const int lo = sb * epb1, hi = min(lo + epb1, EE);
    for (int i = lo + tid; i < hi; i += 256) {
      unsigned sd = sd32[i];
      unsigned buk = (sd & 0xFFFFu) >> 7;
      unsigned slot = atomicAdd(&cur[buk], 1u);
      ebuk[slot] = sd;
    }
  }
}

// Dispatch 4: per-bucket CSR build: deg + row_start (coalesced) + csr16.
__global__ __launch_bounds__(256)
void csr_build_kernel(int N, int nbuk,
                      const unsigned* __restrict__ buktotal,
                      const unsigned* __restrict__ ebuk,
                      unsigned* __restrict__ deg, unsigned* __restrict__ row_start,
                      unsigned short* __restrict__ csr16)
{
  __shared__ unsigned bt[NBUKMAX], bs[NBUKMAX];
  __shared__ unsigned ps[256];
  __shared__ unsigned hist[128], hs[128], cur2[128];
  const int j = blockIdx.x;
  const int tid = threadIdx.x;

  bukstart_scan(buktotal, nbuk, bt, ps, bs, tid);
  const unsigned estart = bs[j];
  const unsigned ecount = bt[j];
  const int n0 = j * 128;

  if (tid < 128) hist[tid] = 0;
  __syncthreads();
  for (unsigned i = estart + tid; i < estart + ecount; i += 256)
    atomicAdd(&hist[ebuk[i] & 127u], 1u);
  __syncthreads();
  unsigned hv = (tid < 128) ? hist[tid] : 0u;
  if (tid < 128) hs[tid] = hv;
  __syncthreads();
  for (int off = 1; off < 128; off <<= 1) {
    unsigned v = 0;
    if (tid < 128 && tid >= off) v = hs[tid - off];
    __syncthreads();
    if (tid < 128) hs[tid] += v;
    __syncthreads();
  }
  if (tid < 128) {
    unsigned excl = hs[tid] - hv;
    cur2[tid] = estart + excl;
    if (n0 + tid < N) {
      deg[n0 + tid] = hv;
      row_start[n0 + tid] = estart + excl;
    }
  }
  __syncthreads();
  for (unsigned i = estart + tid; i < estart + ecount; i += 256) {
    unsigned sd = ebuk[i];
    unsigned slot = atomicAdd(&cur2[sd & 127u], 1u);
    csr16[slot] = (unsigned short)(sd >> 16);
  }
}

// ---------------------------------------------------------------------------
// Dispatch 5: FUSED aggregate layer-1 + gemm layer-2 + layer-2 att dots.
// Aggregate loops run to each group's OWN cnt (divergent; exec-masked lanes
// issue no vmem) -- no clamped padding loads, no wave-max.
__global__ __launch_bounds__(256)
void agg1_gemm2_kernel(const unsigned* __restrict__ row_start,
                       const unsigned* __restrict__ deg,
                       const unsigned short* __restrict__ csr16,
                       const __half* __restrict__ h,
                       const float* __restrict__ a_src,
                       const float* __restrict__ a_dst,
                       const float* __restrict__ bias,
                       const _Float16* __restrict__ W2T,
                       const float* __restrict__ as2, const float* __restrict__ ad2,
                       _Float16* __restrict__ h2,
                       float* __restrict__ asv2, float* __restrict__ adv2, int N)
{
  __shared__ _Float16 actS[16][132];
  __shared__ float sdots[2][16];

  const int lane = threadIdx.x & 63;
  const int wid  = threadIdx.x >> 6;
  const int l5   = lane & 15;
  const int nl   = wid * 4 + (lane >> 4);
  const int nb   = blockIdx.x * 16;
  const int n    = nb + nl;
  const int nn   = min(n, N - 1);
  const int hd   = l5 >> 2;

  // phase 1: aggregate (H=4), per-group cnt loop
  const float adn = a_dst[(size_t)nn * 4 + hd];
  const unsigned beg = row_start[nn];
  const unsigned cnt = deg[nn];

  const float4* __restrict__ h4 = (const float4*)h;

  float Z = 0.f;
  float acc[8];
#pragma unroll
  for (int j = 0; j < 8; ++j) acc[j] = 0.f;

  unsigned i = 0;
  for (; i + 4 <= cnt; i += 4) {
    unsigned s0 = csr16[beg + i];
    unsigned s1 = csr16[beg + i + 1];
    unsigned s2 = csr16[beg + i + 2];
    unsigned s3 = csr16[beg + i + 3];
    float e0 = a_src[(size_t)s0 * 4 + hd] + adn;
    float e1 = a_src[(size_t)s1 * 4 + hd] + adn;
    float e2 = a_src[(size_t)s2 * 4 + hd] + adn;
    float e3 = a_src[(size_t)s3 * 4 + hd] + adn;
    float4 v0 = h4[(size_t)s0 * 16 + l5];
    float4 v1 = h4[(size_t)s1 * 16 + l5];
    float4 v2 = h4[(size_t)s2 * 16 + l5];
    float4 v3 = h4[(size_t)s3 * 16 + l5];
    e0 = (e0 >= 0.f) ? e0 : SLOPE_ATT * e0;
    e1 = (e1 >= 0.f) ? e1 : SLOPE_ATT * e1;
    e2 = (e2 >= 0.f) ? e2 : SLOPE_ATT * e2;
    e3 = (e3 >= 0.f) ? e3 : SLOPE_ATT * e3;
    float w0 = __expf(e0), w1 = __expf(e1), w2 = __expf(e2), w3 = __expf(e3);
    Z += (w0 + w1) + (w2 + w3);
    const __half2* q0 = (const __half2*)&v0;
    const __half2* q1 = (const __half2*)&v1;
    const __half2* q2 = (const __half2*)&v2;
    const __half2* q3 = (const __half2*)&v3;
#pragma unroll
    for (int j = 0; j < 4; ++j) {
      float2 f0 = __half22float2(q0[j]);
      float2 f1 = __half22float2(q1[j]);
      float2 f2 = __half22float2(q2[j]);
      float2 f3 = __half22float2(q3[j]);
      acc[2*j]   += w0 * f0.x + w1 * f1.x + w2 * f2.x + w3 * f3.x;
      acc[2*j+1] += w0 * f0.y + w1 * f1.y + w2 * f2.y + w3 * f3.y;
    }
  }
  for (; i < cnt; ++i) {
    unsigned s0 = csr16[beg + i];
    float e0 = a_src[(size_t)s0 * 4 + hd] + adn;
    float4 v0 = h4[(size_t)s0 * 16 + l5];
    e0 = (e0 >= 0.f) ? e0 : SLOPE_ATT * e0;
    float w0 = __expf(e0);
    Z += w0;
    const __half2* q0 = (const __half2*)&v0;
#pragma unroll
    for (int j = 0; j < 4; ++j) {
      float2 f0 = __half22float2(q0[j]);
      acc[2*j]   += w0 * f0.x;
      acc[2*j+1] += w0 * f0.y;
    }
  }

  const float inv = 1.f / (Z + 1e-16f);
  float4 b0 = ((const float4*)bias)[l5 * 2];
  float4 b1 = ((const float4*)bias)[l5 * 2 + 1];
  float o[8];
  o[0] = acc[0] * inv + b0.x;  o[1] = acc[1] * inv + b0.y;
  o[2] = acc[2] * inv + b0.z;  o[3] = acc[3] * inv + b0.w;
  o[4] = acc[4] * inv + b1.x;  o[5] = acc[5] * inv + b1.y;
  o[6] = acc[6] * inv + b1.z;  o[7] = acc[7] * inv + b1.w;
#pragma unroll
  for (int j = 0; j < 8; ++j) o[j] = (o[j] >= 0.f) ? o[j] : SLOPE_ACT * o[j];

  // phase 2: stage act1
#pragma unroll
  for (int j = 0; j < 8; ++j) actS[nl][l5 * 8 + j] = (_Float16)o[j];
  if (threadIdx.x < 32) sdots[threadIdx.x >> 4][threadIdx.x & 15] = 0.f;
  __syncthreads();

  // phase 3: mini-GEMM h2 = act1 @ W2 + H=1 dots
  const int li = l5;
  const int lk = lane >> 4;
#pragma unroll
  for (int t = 0; t < 2; ++t) {
    const int c0 = wid * 32 + t * 16;
    f32x4 a2 = (f32x4){0.f, 0.f, 0.f, 0.f};
#pragma unroll
    for (int ks = 0; ks < 4; ++ks) {
      hf8 af = *(const hf8*)&actS[li][ks * 32 + lk * 8];
      hf8 bf = *(const hf8*)&W2T[(size_t)(c0 + li) * 128 + ks * 32 + lk * 8];
      a2 = __builtin_amdgcn_mfma_f32_16x16x32_f16(af, bf, a2, 0, 0, 0);
    }
    const float asc = as2[c0 + li];
    const float adc = ad2[c0 + li];
#pragma unroll
    for (int reg = 0; reg < 4; ++reg) {
      const int r = lk * 4 + reg;
      float hv = a2[reg];
      if (nb + r < N) h2[(size_t)(nb + r) * 128 + c0 + li] = (_Float16)hv;
      float sp = hv * asc;
      float dp = hv * adc;
      sp += __shfl_xor(sp, 1); sp += __shfl_xor(sp, 2);
      sp += __shfl_xor(sp, 4); sp += __shfl_xor(sp, 8);
      dp += __shfl_xor(dp, 1); dp += __shfl_xor(dp, 2);
      dp += __shfl_xor(dp, 4); dp += __shfl_xor(dp, 8);
      if (li == 0) {
        atomicAdd(&sdots[0][r], sp);
        atomicAdd(&sdots[1][r], dp);
      }
    }
  }
  __syncthreads();
  if (threadIdx.x < 16) {
    const int r = threadIdx.x;
    if (nb + r < N) {
      asv2[nb + r] = sdots[0][r];
      adv2[nb + r] = sdots[1][r];
    }
  }
}

// ---------------------------------------------------------------------------
// Dispatch 6: aggregate layer-2 (H=1, fp32 out) -> d_out. Per-group cnt loop.
__global__ __launch_bounds__(256)
void aggregate2_kernel(const unsigned* __restrict__ row_start,
                       const unsigned* __restrict__ deg,
                       const unsigned short* __restrict__ csr16,
                       const __half* __restrict__ h,
                       const float* __restrict__ a_src,
                       const float* __restrict__ a_dst,
                       const float* __restrict__ bias,
                       float* __restrict__ out, int N)
{
  const int lane = threadIdx.x & 63;
  const int wid  = threadIdx.x >> 6;
  const int l5   = lane & 15;
  const int n    = blockIdx.x * 16 + wid * 4 + (lane >> 4);
  const int nn   = min(n, N - 1);

  const float adn = a_dst[nn];
  const unsigned beg = row_start[nn];
  const unsigned cnt = deg[nn];

  const float4* __restrict__ h4 = (const float4*)h;

  float Z = 0.f;
  float acc[8];
#pragma unroll
  for (int j = 0; j < 8; ++j) acc[j] = 0.f;

  unsigned i = 0;
  for (; i + 4 <= cnt; i += 4) {
    unsigned s0 = csr16[beg + i];
    unsigned s1 = csr16[beg + i + 1];
    unsigned s2 = csr16[beg + i + 2];
    unsigned s3 = csr16[beg + i + 3];
    float e0 = a_src[s0] + adn;
    float e1 = a_src[s1] + adn;
    float e2 = a_src[s2] + adn;
    float e3 = a_src[s3] + adn;
    float4 v0 = h4[(size_t)s0 * 16 + l5];
    float4 v1 = h4[(size_t)s1 * 16 + l5];
    float4 v2 = h4[(size_t)s2 * 16 + l5];
    float4 v3 = h4[(size_t)s3 * 16 + l5];
    e0 = (e0 >= 0.f) ? e0 : SLOPE_ATT * e0;
    e1 = (e1 >= 0.f) ? e1 : SLOPE_ATT * e1;
    e2 = (e2 >= 0.f) ? e2 : SLOPE_ATT * e2;
    e3 = (e3 >= 0.f) ? e3 : SLOPE_ATT * e3;
    float w0 = __expf(e0), w1 = __expf(e1), w2 = __expf(e2), w3 = __expf(e3);
    Z += (w0 + w1) + (w2 + w3);
    const __half2* q0 = (const __half2*)&v0;
    const __half2* q1 = (const __half2*)&v1;
    const __half2* q2 = (const __half2*)&v2;
    const __half2* q3 = (const __half2*)&v3;
#pragma unroll
    for (int j = 0; j < 4; ++j) {
      float2 f0 = __half22float2(q0[j]);
      float2 f1 = __half22float2(q1[j]);
      float2 f2 = __half22float2(q2[j]);
      float2 f3 = __half22float2(q3[j]);
      acc[2*j]   += w0 * f0.x + w1 * f1.x + w2 * f2.x + w3 * f3.x;
      acc[2*j+1] += w0 * f0.y + w1 * f1.y + w2 * f2.y + w3 * f3.y;
    }
  }
  for (; i < cnt; ++i) {
    unsigned s0 = csr16[beg + i];
    float e0 = a_src[s0] + adn;
    float4 v0 = h4[(size_t)s0 * 16 + l5];
    e0 = (e0 >= 0.f) ? e0 : SLOPE_ATT * e0;
    float w0 = __expf(e0);
    Z += w0;
    const __half2* q0 = (const __half2*)&v0;
#pragma unroll
    for (int j = 0; j < 4; ++j) {
      float2 f0 = __half22float2(q0[j]);
      acc[2*j]   += w0 * f0.x;
      acc[2*j+1] += w0 * f0.y;
    }
  }

  const float inv = 1.f / (Z + 1e-16f);
  float4 b0 = ((const float4*)bias)[l5 * 2];
  float4 b1 = ((const float4*)bias)[l5 * 2 + 1];
  float o[8];
  o[0] = acc[0] * inv + b0.x;  o[1] = acc[1] * inv + b0.y;
  o[2] = acc[2] * inv + b0.z;  o[3] = acc[3] * inv + b0.w;
  o[4] = acc[4] * inv + b1.x;  o[5] = acc[5] * inv + b1.y;
  o[6] = acc[6] * inv + b1.z;  o[7] = acc[7] * inv + b1.w;
#pragma unroll
  for (int j = 0; j < 8; ++j) o[j] = (o[j] >= 0.f) ? o[j] : SLOPE_ACT * o[j];

  if (n < N) {
    ((float4*)out)[(size_t)n * 32 + l5 * 2]     = make_float4(o[0], o[1], o[2], o[3]);
    ((float4*)out)[(size_t)n * 32 + l5 * 2 + 1] = make_float4(o[4], o[5], o[6], o[7]);
  }
}

// ---------------------------------------------------------------------------
extern "C" void kernel_launch(void* const* d_in, const int* in_sizes, int n_in,
                              void* d_out, int out_size, void* d_ws, size_t ws_size,
                              hipStream_t stream)
{
  const float* x   = (const float*)d_in[0];
  const int*   ei  = (const int*)d_in[1];
  const float* W1  = (const float*)d_in[2];
  const float* as1 = (const float*)d_in[3];
  const float* ad1 = (const float*)d_in[4];
  const float* b1  = (const float*)d_in[5];
  const float* W2  = (const float*)d_in[6];
  const float* as2 = (const float*)d_in[7];
  const float* ad2 = (const float*)d_in[8];
  const float* b2  = (const float*)d_in[9];
  float* out = (float*)d_out;

  const int N  = in_sizes[0] / 256;
  const int E  = in_sizes[1] / 2;
  const int EE = E + N;
  const int nbuk = (N + 127) / 128;            // <= 512 for N <= 65536
  const int epb1 = (EE + SB - 1) / SB;         // edges per count/scatter block
  const int pgrid = (EE + 255) / 256;          // packing blocks

  float* ws = (float*)d_ws;
  size_t o = 0;
  _Float16* h    = (_Float16*)(ws + o); o += (size_t)N * 64;   // layer-1 h [N][128] fp16
  _Float16* h2   = (_Float16*)(ws + o); o += (size_t)N * 64;   // layer-2 h [N][128] fp16
  float* asv  = ws + o; o += (size_t)N * 4;                    // layer-1 dots (H=4)
  float* adv  = ws + o; o += (size_t)N * 4;
  float* asv2 = ws + o; o += (size_t)N;                        // layer-2 dots (H=1)
  float* adv2 = ws + o; o += (size_t)N;
  _Float16* W1T = (_Float16*)(ws + o); o += 128 * 256 / 2;     // [128][256] fp16
  _Float16* W2T = (_Float16*)(ws + o); o += 128 * 128 / 2;     // [128][128] fp16
  unsigned* deg       = (unsigned*)(ws + o); o += (size_t)N;
  unsigned* row_start = (unsigned*)(ws + o); o += (size_t)N;
  unsigned* cntA      = (unsigned*)(ws + o); o += (size_t)SB * NBUKMAX;   // 512 KB
  unsigned* blkoff    = (unsigned*)(ws + o); o += (size_t)SB * NBUKMAX;   // 512 KB
  unsigned* buktotal  = (unsigned*)(ws + o); o += NBUKMAX;
  unsigned* sd32      = (unsigned*)(ws + o); o += (size_t)EE;             // 3.4 MB
  unsigned* ebuk      = (unsigned*)(ws + o); o += (size_t)EE;             // 3.4 MB
  unsigned short* csr16 = (unsigned short*)(ws + o); o += (size_t)(EE + 1) / 2; // 1.7 MB

  const int ngrid = (N + 15) / 16;
  const int ggrid = (N + 127) / 128;

  // 1) bucket count || convW1 || convW2 || sd32 pack
  pre_kernel<<<SB + 192 + pgrid, 256, 0, stream>>>(
      ei, E, N, nbuk, epb1, cntA, sd32, W1, W1T, W2, W2T);
  // 2) per-bucket column scan
  bukoff_kernel<<<nbuk, 256, 0, stream>>>(cntA, blkoff, buktotal);
  // 3) gemm layer-1 || bucket scatter
  gemm1_scatter_kernel<<<ggrid + SB, 256, 0, stream>>>(
      E, N, nbuk, epb1, sd32, blkoff, buktotal, ebuk,
      x, W1T, as1, ad1, h, asv, adv, ggrid);
  // 4) per-bucket CSR build (deg + row_start + csr16, all bucket-local)
  csr_build_kernel<<<nbuk, 256, 0, stream>>>(
      N, nbuk, buktotal, ebuk, deg, row_start, csr16);
  // 5) aggregate layer-1 + gemm layer-2 + layer-2 dots (fused)
  agg1_gemm2_kernel<<<ngrid, 256, 0, stream>>>(
      row_start, deg, csr16, (const __half*)h, asv, adv, b1,
      W2T, as2, ad2, h2, asv2, adv2, N);
  // 6) aggregate layer-2 -> out (fp32)
  aggregate2_kernel<<<ngrid, 256, 0, stream>>>(
      row_start, deg, csr16, (const __half*)h2, asv2, adv2, b2, out, N);
}

// Round 19
// 140.623 us; speedup vs baseline: 1.1955x; 1.0150x over previous
//
#include <hip/hip_runtime.h>
#include <hip/hip_fp16.h>

#define SLOPE_ATT 0.2f
#define SLOPE_ACT 0.01f

#define SB 256        // edge-range blocks for count/scatter
#define NBUKMAX 512   // max coarse buckets (dst>>7, N<=65536)

typedef _Float16 hf8 __attribute__((ext_vector_type(8)));
typedef float f32x4 __attribute__((ext_vector_type(4)));

// ---------------------------------------------------------------------------
// MFMA fp16 GEMM body: h[M][128] = A[M][K] @ B[K][128], BT[128][K] fp16.
template<int K, int H, bool A_FP32>
__device__ __forceinline__
void gemm_mfma_body(int gbid, int tid,
                    const void* __restrict__ Av, const _Float16* __restrict__ BT,
                    const float* __restrict__ att_s, const float* __restrict__ att_d,
                    _Float16* __restrict__ hout, float* __restrict__ a_src,
                    float* __restrict__ a_dst, int M)
{
  const int lane = tid & 63;
  const int wid  = tid >> 6;
  const int li   = lane & 15;
  const int lk   = lane >> 4;
  const int rowbase = gbid * 128 + wid * 32;

  const float*    Af = (const float*)Av;
  const _Float16* Ah = (const _Float16*)Av;

  f32x4 acc[2][8];
#pragma unroll
  for (int i = 0; i < 2; ++i)
#pragma unroll
    for (int j = 0; j < 8; ++j) acc[i][j] = (f32x4){0.f, 0.f, 0.f, 0.f};

  const int r0 = min(rowbase + li,      M - 1);
  const int r1 = min(rowbase + 16 + li, M - 1);

#pragma unroll
  for (int ks = 0; ks < K / 32; ++ks) {
    const int kb = ks * 32 + lk * 8;
    hf8 a0, a1;
    if constexpr (A_FP32) {
      const float* p0 = &Af[(size_t)r0 * K + kb];
      const float* p1 = &Af[(size_t)r1 * K + kb];
      float4 x0a = *(const float4*)p0, x0b = *(const float4*)(p0 + 4);
      float4 x1a = *(const float4*)p1, x1b = *(const float4*)(p1 + 4);
      a0[0]=(_Float16)x0a.x; a0[1]=(_Float16)x0a.y; a0[2]=(_Float16)x0a.z; a0[3]=(_Float16)x0a.w;
      a0[4]=(_Float16)x0b.x; a0[5]=(_Float16)x0b.y; a0[6]=(_Float16)x0b.z; a0[7]=(_Float16)x0b.w;
      a1[0]=(_Float16)x1a.x; a1[1]=(_Float16)x1a.y; a1[2]=(_Float16)x1a.z; a1[3]=(_Float16)x1a.w;
      a1[4]=(_Float16)x1b.x; a1[5]=(_Float16)x1b.y; a1[6]=(_Float16)x1b.z; a1[7]=(_Float16)x1b.w;
    } else {
      a0 = *(const hf8*)&Ah[(size_t)r0 * K + kb];
      a1 = *(const hf8*)&Ah[(size_t)r1 * K + kb];
    }
#pragma unroll
    for (int cf = 0; cf < 8; ++cf) {
      hf8 b = *(const hf8*)&BT[(size_t)(cf * 16 + li) * K + kb];
      acc[0][cf] = __builtin_amdgcn_mfma_f32_16x16x32_f16(a0, b, acc[0][cf], 0, 0, 0);
      acc[1][cf] = __builtin_amdgcn_mfma_f32_16x16x32_f16(a1, b, acc[1][cf], 0, 0, 0);
    }
  }

  float sA[8], dA[8];
#pragma unroll
  for (int cf = 0; cf < 8; ++cf) {
    sA[cf] = att_s[cf * 16 + li];
    dA[cf] = att_d[cf * 16 + li];
  }

  const bool full = (rowbase + 32) <= M;
#pragma unroll
  for (int rf = 0; rf < 2; ++rf) {
    const int rb = rowbase + rf * 16 + lk * 4;
#pragma unroll
    for (int reg = 0; reg < 4; ++reg) {
      const int r = rb + reg;
      if (full || r < M) {
#pragma unroll
        for (int cf = 0; cf < 8; ++cf)
          hout[(size_t)r * 128 + cf * 16 + li] = (_Float16)acc[rf][cf][reg];
      }
    }
    if constexpr (H == 4) {
#pragma unroll
      for (int hh = 0; hh < 4; ++hh) {
#pragma unroll
        for (int reg = 0; reg < 4; ++reg) {
          float sp = acc[rf][2*hh][reg] * sA[2*hh] + acc[rf][2*hh+1][reg] * sA[2*hh+1];
          float dp = acc[rf][2*hh][reg] * dA[2*hh] + acc[rf][2*hh+1][reg] * dA[2*hh+1];
          sp += __shfl_xor(sp, 1); sp += __shfl_xor(sp, 2);
          sp += __shfl_xor(sp, 4); sp += __shfl_xor(sp, 8);
          dp += __shfl_xor(dp, 1); dp += __shfl_xor(dp, 2);
          dp += __shfl_xor(dp, 4); dp += __shfl_xor(dp, 8);
          const int r = rb + reg;
          if (li == 0 && r < M) {
            a_src[(size_t)r * 4 + hh] = sp;
            a_dst[(size_t)r * 4 + hh] = dp;
          }
        }
      }
    } else {
#pragma unroll
      for (int reg = 0; reg < 4; ++reg) {
        float sp = 0.f, dp = 0.f;
#pragma unroll
        for (int cf = 0; cf < 8; ++cf) {
          sp += acc[rf][cf][reg] * sA[cf];
          dp += acc[rf][cf][reg] * dA[cf];
        }
        sp += __shfl_xor(sp, 1); sp += __shfl_xor(sp, 2);
        sp += __shfl_xor(sp, 4); sp += __shfl_xor(sp, 8);
        dp += __shfl_xor(dp, 1); dp += __shfl_xor(dp, 2);
        dp += __shfl_xor(dp, 4); dp += __shfl_xor(dp, 8);
        const int r = rb + reg;
        if (li == 0 && r < M) { a_src[r] = sp; a_dst[r] = dp; }
      }
    }
  }
}

// ---------------------------------------------------------------------------
// Dispatch 1: coarse bucket count || convW1 || convW2 || sd32 pack.
__global__ __launch_bounds__(256)
void pre_kernel(const int* __restrict__ ei, int E, int N, int nbuk, int epb1,
                unsigned* __restrict__ cntA, unsigned* __restrict__ sd32,
                const float* __restrict__ W1, _Float16* __restrict__ W1T,
                const float* __restrict__ W2, _Float16* __restrict__ W2T)
{
  __shared__ unsigned hist[NBUKMAX];
  const int bid = blockIdx.x;
  const int tid = threadIdx.x;
  if (bid < SB) {
    for (int j = tid; j < NBUKMAX; j += 256) hist[j] = 0;
    __syncthreads();
    const int EE = E + N;
    const int lo = bid * epb1, hi = min(lo + epb1, EE);
    for (int i = lo + tid; i < hi; i += 256) {
      int d = (i < E) ? ei[E + i] : (i - E);
      atomicAdd(&hist[d >> 7], 1u);
    }
    __syncthreads();
    for (int j = tid; j < nbuk; j += 256)
      cntA[(size_t)bid * NBUKMAX + j] = hist[j];
  } else if (bid < SB + 128) {          // W1: 256x128
    int idx = (bid - SB) * 256 + tid;
    int k = idx >> 7, c = idx & 127;
    W1T[(size_t)c * 256 + k] = (_Float16)W1[idx];
  } else if (bid < SB + 192) {          // W2: 128x128
    int idx = (bid - SB - 128) * 256 + tid;
    int k = idx >> 7, c = idx & 127;
    W2T[(size_t)c * 128 + k] = (_Float16)W2[idx];
  } else {                              // sd32 pack
    const int i = (bid - SB - 192) * 256 + tid;
    const int EE = E + N;
    if (i < EE) {
      unsigned s, d;
      if (i < E) { s = (unsigned)ei[i]; d = (unsigned)ei[E + i]; }
      else       { s = d = (unsigned)(i - E); }
      sd32[i] = (s << 16) | d;
    }
  }
}

// Dispatch 2: per-bucket column scan of cntA -> blkoff (exclusive), buktotal.
__global__ __launch_bounds__(256)
void bukoff_kernel(const unsigned* __restrict__ cntA, unsigned* __restrict__ blkoff,
                   unsigned* __restrict__ buktotal)
{
  __shared__ unsigned s[256];
  const int j = blockIdx.x;
  const int t = threadIdx.x;
  unsigned v0 = cntA[(size_t)t * NBUKMAX + j];
  s[t] = v0;
  __syncthreads();
  for (int off = 1; off < 256; off <<= 1) {
    unsigned v = (t >= off) ? s[t - off] : 0u;
    __syncthreads();
    s[t] += v;
    __syncthreads();
  }
  blkoff[(size_t)t * NBUKMAX + j] = s[t] - v0;
  if (t == 255) buktotal[j] = s[255];
}

// Inline exclusive scan of buktotal[0..nbuk) -> bs[0..nbuk).
__device__ __forceinline__
void bukstart_scan(const unsigned* __restrict__ buktotal, int nbuk,
                   unsigned* bt, unsigned* ps, unsigned* bs, int tid)
{
  for (int j = tid; j < NBUKMAX; j += 256) bt[j] = (j < nbuk) ? buktotal[j] : 0u;
  __syncthreads();
  unsigned pair = bt[2 * tid] + bt[2 * tid + 1];
  ps[tid] = pair;
  __syncthreads();
  for (int off = 1; off < 256; off <<= 1) {
    unsigned v = (tid >= off) ? ps[tid - off] : 0u;
    __syncthreads();
    ps[tid] += v;
    __syncthreads();
  }
  unsigned e0 = ps[tid] - pair;
  bs[2 * tid]     = e0;
  bs[2 * tid + 1] = e0 + bt[2 * tid];
  __syncthreads();
}

// Dispatch 3: gemm layer-1 || bucket scatter (edges -> ebuk grouped by bucket).
__global__ __launch_bounds__(256)
void gemm1_scatter_kernel(int E, int N, int nbuk, int epb1,
                          const unsigned* __restrict__ sd32,
                          const unsigned* __restrict__ blkoff,
                          const unsigned* __restrict__ buktotal,
                          unsigned* __restrict__ ebuk,
                          const float* __restrict__ x, const _Float16* __restrict__ W1T,
                          const float* __restrict__ as1, const float* __restrict__ ad1,
                          _Float16* __restrict__ h, float* __restrict__ asv,
                          float* __restrict__ adv, int ggrid)
{
  __shared__ unsigned bt[NBUKMAX], bs[NBUKMAX], cur[NBUKMAX];
  __shared__ unsigned ps[256];
  const int bid = blockIdx.x;
  const int tid = threadIdx.x;
  if (bid < ggrid) {
    gemm_mfma_body<256, 4, true>(bid, tid, x, W1T, as1, ad1, h, asv, adv, N);
  } else {
    const int sb = bid - ggrid;
    bukstart_scan(buktotal, nbuk, bt, ps, bs, tid);
    for (int j = tid; j < nbuk; j += 256)
      cur[j] = bs[j] + blkoff[(size_t)sb * NBUKMAX + j];
    __syncthreads();
    const int EE = E + N;
    const int lo = sb * epb1, hi = min(lo + epb1, EE);
    for (int i = lo + tid; i < hi; i += 256) {
      unsigned sd = sd32[i];
      unsigned buk = (sd & 0xFFFFu) >> 7;
      unsigned slot = atomicAdd(&cur[buk], 1u);
      ebuk[slot] = sd;
    }
  }
}

// Dispatch 4: per-bucket CSR build: deg + row_start (coalesced) + csr16.
__global__ __launch_bounds__(256)
void csr_build_kernel(int N, int nbuk,
                      const unsigned* __restrict__ buktotal,
                      const unsigned* __restrict__ ebuk,
                      unsigned* __restrict__ deg, unsigned* __restrict__ row_start,
                      unsigned short* __restrict__ csr16)
{
  __shared__ unsigned bt[NBUKMAX], bs[NBUKMAX];
  __shared__ unsigned ps[256];
  __shared__ unsigned hist[128], hs[128], cur2[128];
  const int j = blockIdx.x;
  const int tid = threadIdx.x;

  bukstart_scan(buktotal, nbuk, bt, ps, bs, tid);
  const unsigned estart = bs[j];
  const unsigned ecount = bt[j];
  const int n0 = j * 128;

  if (tid < 128) hist[tid] = 0;
  __syncthreads();
  for (unsigned i = estart + tid; i < estart + ecount; i += 256)
    atomicAdd(&hist[ebuk[i] & 127u], 1u);
  __syncthreads();
  unsigned hv = (tid < 128) ? hist[tid] : 0u;
  if (tid < 128) hs[tid] = hv;
  __syncthreads();
  for (int off = 1; off < 128; off <<= 1) {
    unsigned v = 0;
    if (tid < 128 && tid >= off) v = hs[tid - off];
    __syncthreads();
    if (tid < 128) hs[tid] += v;
    __syncthreads();
  }
  if (tid < 128) {
    unsigned excl = hs[tid] - hv;
    cur2[tid] = estart + excl;
    if (n0 + tid < N) {
      deg[n0 + tid] = hv;
      row_start[n0 + tid] = estart + excl;
    }
  }
  __syncthreads();
  for (unsigned i = estart + tid; i < estart + ecount; i += 256) {
    unsigned sd = ebuk[i];
    unsigned slot = atomicAdd(&cur2[sd & 127u], 1u);
    csr16[slot] = (unsigned short)(sd >> 16);
  }
}

// ---------------------------------------------------------------------------
// Dispatch 5: FUSED aggregate layer-1 + gemm layer-2 + layer-2 att dots.
// Index stream software-pipelined: next block's 4 src indices are loaded
// before the current block's gathers are consumed.
__global__ __launch_bounds__(256)
void agg1_gemm2_kernel(const unsigned* __restrict__ row_start,
                       const unsigned* __restrict__ deg,
                       const unsigned short* __restrict__ csr16,
                       const __half* __restrict__ h,
                       const float* __restrict__ a_src,
                       const float* __restrict__ a_dst,
                       const float* __restrict__ bias,
                       const _Float16* __restrict__ W2T,
                       const float* __restrict__ as2, const float* __restrict__ ad2,
                       _Float16* __restrict__ h2,
                       float* __restrict__ asv2, float* __restrict__ adv2, int N)
{
  __shared__ _Float16 actS[16][132];
  __shared__ float sdots[2][16];

  const int lane = threadIdx.x & 63;
  const int wid  = threadIdx.x >> 6;
  const int l5   = lane & 15;
  const int nl   = wid * 4 + (lane >> 4);
  const int nb   = blockIdx.x * 16;
  const int n    = nb + nl;
  const int nn   = min(n, N - 1);
  const int hd   = l5 >> 2;

  // phase 1: aggregate (H=4), pipelined index stream
  const float adn = a_dst[(size_t)nn * 4 + hd];
  const unsigned beg = row_start[nn];
  const unsigned cnt = deg[nn];

  const float4* __restrict__ h4 = (const float4*)h;

  float Z = 0.f;
  float acc[8];
#pragma unroll
  for (int j = 0; j < 8; ++j) acc[j] = 0.f;

  unsigned cs0, cs1, cs2, cs3;
  unsigned i = 0;
  if (i + 4 <= cnt) {
    cs0 = csr16[beg];     cs1 = csr16[beg + 1];
    cs2 = csr16[beg + 2]; cs3 = csr16[beg + 3];
  }
  while (i + 4 <= cnt) {
    const unsigned s0 = cs0, s1 = cs1, s2 = cs2, s3 = cs3;
    const unsigned ni = i + 4;
    if (ni + 4 <= cnt) {
      cs0 = csr16[beg + ni];     cs1 = csr16[beg + ni + 1];
      cs2 = csr16[beg + ni + 2]; cs3 = csr16[beg + ni + 3];
    }
    float e0 = a_src[(size_t)s0 * 4 + hd] + adn;
    float e1 = a_src[(size_t)s1 * 4 + hd] + adn;
    float e2 = a_src[(size_t)s2 * 4 + hd] + adn;
    float e3 = a_src[(size_t)s3 * 4 + hd] + adn;
    float4 v0 = h4[(size_t)s0 * 16 + l5];
    float4 v1 = h4[(size_t)s1 * 16 + l5];
    float4 v2 = h4[(size_t)s2 * 16 + l5];
    float4 v3 = h4[(size_t)s3 * 16 + l5];
    e0 = (e0 >= 0.f) ? e0 : SLOPE_ATT * e0;
    e1 = (e1 >= 0.f) ? e1 : SLOPE_ATT * e1;
    e2 = (e2 >= 0.f) ? e2 : SLOPE_ATT * e2;
    e3 = (e3 >= 0.f) ? e3 : SLOPE_ATT * e3;
    float w0 = __expf(e0), w1 = __expf(e1), w2 = __expf(e2), w3 = __expf(e3);
    Z += (w0 + w1) + (w2 + w3);
    const __half2* q0 = (const __half2*)&v0;
    const __half2* q1 = (const __half2*)&v1;
    const __half2* q2 = (const __half2*)&v2;
    const __half2* q3 = (const __half2*)&v3;
#pragma unroll
    for (int j = 0; j < 4; ++j) {
      float2 f0 = __half22float2(q0[j]);
      float2 f1 = __half22float2(q1[j]);
      float2 f2 = __half22float2(q2[j]);
      float2 f3 = __half22float2(q3[j]);
      acc[2*j]   += w0 * f0.x + w1 * f1.x + w2 * f2.x + w3 * f3.x;
      acc[2*j+1] += w0 * f0.y + w1 * f1.y + w2 * f2.y + w3 * f3.y;
    }
    i = ni;
  }
  for (; i < cnt; ++i) {
    unsigned s0 = csr16[beg + i];
    float e0 = a_src[(size_t)s0 * 4 + hd] + adn;
    float4 v0 = h4[(size_t)s0 * 16 + l5];
    e0 = (e0 >= 0.f) ? e0 : SLOPE_ATT * e0;
    float w0 = __expf(e0);
    Z += w0;
    const __half2* q0 = (const __half2*)&v0;
#pragma unroll
    for (int j = 0; j < 4; ++j) {
      float2 f0 = __half22float2(q0[j]);
      acc[2*j]   += w0 * f0.x;
      acc[2*j+1] += w0 * f0.y;
    }
  }

  const float inv = 1.f / (Z + 1e-16f);
  float4 b0 = ((const float4*)bias)[l5 * 2];
  float4 b1 = ((const float4*)bias)[l5 * 2 + 1];
  float o[8];
  o[0] = acc[0] * inv + b0.x;  o[1] = acc[1] * inv + b0.y;
  o[2] = acc[2] * inv + b0.z;  o[3] = acc[3] * inv + b0.w;
  o[4] = acc[4] * inv + b1.x;  o[5] = acc[5] * inv + b1.y;
  o[6] = acc[6] * inv + b1.z;  o[7] = acc[7] * inv + b1.w;
#pragma unroll
  for (int j = 0; j < 8; ++j) o[j] = (o[j] >= 0.f) ? o[j] : SLOPE_ACT * o[j];

  // phase 2: stage act1
#pragma unroll
  for (int j = 0; j < 8; ++j) actS[nl][l5 * 8 + j] = (_Float16)o[j];
  if (threadIdx.x < 32) sdots[threadIdx.x >> 4][threadIdx.x & 15] = 0.f;
  __syncthreads();

  // phase 3: mini-GEMM h2 = act1 @ W2 + H=1 dots
  const int li = l5;
  const int lk = lane >> 4;
#pragma unroll
  for (int t = 0; t < 2; ++t) {
    const int c0 = wid * 32 + t * 16;
    f32x4 a2 = (f32x4){0.f, 0.f, 0.f, 0.f};
#pragma unroll
    for (int ks = 0; ks < 4; ++ks) {
      hf8 af = *(const hf8*)&actS[li][ks * 32 + lk * 8];
      hf8 bf = *(const hf8*)&W2T[(size_t)(c0 + li) * 128 + ks * 32 + lk * 8];
      a2 = __builtin_amdgcn_mfma_f32_16x16x32_f16(af, bf, a2, 0, 0, 0);
    }
    const float asc = as2[c0 + li];
    const float adc = ad2[c0 + li];
#pragma unroll
    for (int reg = 0; reg < 4; ++reg) {
      const int r = lk * 4 + reg;
      float hv = a2[reg];
      if (nb + r < N) h2[(size_t)(nb + r) * 128 + c0 + li] = (_Float16)hv;
      float sp = hv * asc;
      float dp = hv * adc;
      sp += __shfl_xor(sp, 1); sp += __shfl_xor(sp, 2);
      sp += __shfl_xor(sp, 4); sp += __shfl_xor(sp, 8);
      dp += __shfl_xor(dp, 1); dp += __shfl_xor(dp, 2);
      dp += __shfl_xor(dp, 4); dp += __shfl_xor(dp, 8);
      if (li == 0) {
        atomicAdd(&sdots[0][r], sp);
        atomicAdd(&sdots[1][r], dp);
      }
    }
  }
  __syncthreads();
  if (threadIdx.x < 16) {
    const int r = threadIdx.x;
    if (nb + r < N) {
      asv2[nb + r] = sdots[0][r];
      adv2[nb + r] = sdots[1][r];
    }
  }
}

// ---------------------------------------------------------------------------
// Dispatch 6: aggregate layer-2 (H=1, fp32 out) -> d_out. Pipelined indices.
__global__ __launch_bounds__(256)
void aggregate2_kernel(const unsigned* __restrict__ row_start,
                       const unsigned* __restrict__ deg,
                       const unsigned short* __restrict__ csr16,
                       const __half* __restrict__ h,
                       const float* __restrict__ a_src,
                       const float* __restrict__ a_dst,
                       const float* __restrict__ bias,
                       float* __restrict__ out, int N)
{
  const int lane = threadIdx.x & 63;
  const int wid  = threadIdx.x >> 6;
  const int l5   = lane & 15;
  const int n    = blockIdx.x * 16 + wid * 4 + (lane >> 4);
  const int nn   = min(n, N - 1);

  const float adn = a_dst[nn];
  const unsigned beg = row_start[nn];
  const unsigned cnt = deg[nn];

  const float4* __restrict__ h4 = (const float4*)h;

  float Z = 0.f;
  float acc[8];
#pragma unroll
  for (int j = 0; j < 8; ++j) acc[j] = 0.f;

  unsigned cs0, cs1, cs2, cs3;
  unsigned i = 0;
  if (i + 4 <= cnt) {
    cs0 = csr16[beg];     cs1 = csr16[beg + 1];
    cs2 = csr16[beg + 2]; cs3 = csr16[beg + 3];
  }
  while (i + 4 <= cnt) {
    const unsigned s0 = cs0, s1 = cs1, s2 = cs2, s3 = cs3;
    const unsigned ni = i + 4;
    if (ni + 4 <= cnt) {
      cs0 = csr16[beg + ni];     cs1 = csr16[beg + ni + 1];
      cs2 = csr16[beg + ni + 2]; cs3 = csr16[beg + ni + 3];
    }
    float e0 = a_src[s0] + adn;
    float e1 = a_src[s1] + adn;
    float e2 = a_src[s2] + adn;
    float e3 = a_src[s3] + adn;
    float4 v0 = h4[(size_t)s0 * 16 + l5];
    float4 v1 = h4[(size_t)s1 * 16 + l5];
    float4 v2 = h4[(size_t)s2 * 16 + l5];
    float4 v3 = h4[(size_t)s3 * 16 + l5];
    e0 = (e0 >= 0.f) ? e0 : SLOPE_ATT * e0;
    e1 = (e1 >= 0.f) ? e1 : SLOPE_ATT * e1;
    e2 = (e2 >= 0.f) ? e2 : SLOPE_ATT * e2;
    e3 = (e3 >= 0.f) ? e3 : SLOPE_ATT * e3;
    float w0 = __expf(e0), w1 = __expf(e1), w2 = __expf(e2), w3 = __expf(e3);
    Z += (w0 + w1) + (w2 + w3);
    const __half2* q0 = (const __half2*)&v0;
    const __half2* q1 = (const __half2*)&v1;
    const __half2* q2 = (const __half2*)&v2;
    const __half2* q3 = (const __half2*)&v3;
#pragma unroll
    for (int j = 0; j < 4; ++j) {
      float2 f0 = __half22float2(q0[j]);
      float2 f1 = __half22float2(q1[j]);
      float2 f2 = __half22float2(q2[j]);
      float2 f3 = __half22float2(q3[j]);
      acc[2*j]   += w0 * f0.x + w1 * f1.x + w2 * f2.x + w3 * f3.x;
      acc[2*j+1] += w0 * f0.y + w1 * f1.y + w2 * f2.y + w3 * f3.y;
    }
    i = ni;
  }
  for (; i < cnt; ++i) {
    unsigned s0 = csr16[beg + i];
    float e0 = a_src[s0] + adn;
    float4 v0 = h4[(size_t)s0 * 16 + l5];
    e0 = (e0 >= 0.f) ? e0 : SLOPE_ATT * e0;
    float w0 = __expf(e0);
    Z += w0;
    const __half2* q0 = (const __half2*)&v0;
#pragma unroll
    for (int j = 0; j < 4; ++j) {
      float2 f0 = __half22float2(q0[j]);
      acc[2*j]   += w0 * f0.x;
      acc[2*j+1] += w0 * f0.y;
    }
  }

  const float inv = 1.f / (Z + 1e-16f);
  float4 b0 = ((const float4*)bias)[l5 * 2];
  float4 b1 = ((const float4*)bias)[l5 * 2 + 1];
  float o[8];
  o[0] = acc[0] * inv + b0.x;  o[1] = acc[1] * inv + b0.y;
  o[2] = acc[2] * inv + b0.z;  o[3] = acc[3] * inv + b0.w;
  o[4] = acc[4] * inv + b1.x;  o[5] = acc[5] * inv + b1.y;
  o[6] = acc[6] * inv + b1.z;  o[7] = acc[7] * inv + b1.w;
#pragma unroll
  for (int j = 0; j < 8; ++j) o[j] = (o[j] >= 0.f) ? o[j] : SLOPE_ACT * o[j];

  if (n < N) {
    ((float4*)out)[(size_t)n * 32 + l5 * 2]     = make_float4(o[0], o[1], o[2], o[3]);
    ((float4*)out)[(size_t)n * 32 + l5 * 2 + 1] = make_float4(o[4], o[5], o[6], o[7]);
  }
}

// ---------------------------------------------------------------------------
extern "C" void kernel_launch(void* const* d_in, const int* in_sizes, int n_in,
                              void* d_out, int out_size, void* d_ws, size_t ws_size,
                              hipStream_t stream)
{
  const float* x   = (const float*)d_in[0];
  const int*   ei  = (const int*)d_in[1];
  const float* W1  = (const float*)d_in[2];
  const float* as1 = (const float*)d_in[3];
  const float* ad1 = (const float*)d_in[4];
  const float* b1  = (const float*)d_in[5];
  const float* W2  = (const float*)d_in[6];
  const float* as2 = (const float*)d_in[7];
  const float* ad2 = (const float*)d_in[8];
  const float* b2  = (const float*)d_in[9];
  float* out = (float*)d_out;

  const int N  = in_sizes[0] / 256;
  const int E  = in_sizes[1] / 2;
  const int EE = E + N;
  const int nbuk = (N + 127) / 128;            // <= 512 for N <= 65536
  const int epb1 = (EE + SB - 1) / SB;         // edges per count/scatter block
  const int pgrid = (EE + 255) / 256;          // packing blocks

  float* ws = (float*)d_ws;
  size_t o = 0;
  _Float16* h    = (_Float16*)(ws + o); o += (size_t)N * 64;   // layer-1 h [N][128] fp16
  _Float16* h2   = (_Float16*)(ws + o); o += (size_t)N * 64;   // layer-2 h [N][128] fp16
  float* asv  = ws + o; o += (size_t)N * 4;                    // layer-1 dots (H=4)
  float* adv  = ws + o; o += (size_t)N * 4;
  float* asv2 = ws + o; o += (size_t)N;                        // layer-2 dots (H=1)
  float* adv2 = ws + o; o += (size_t)N;
  _Float16* W1T = (_Float16*)(ws + o); o += 128 * 256 / 2;     // [128][256] fp16
  _Float16* W2T = (_Float16*)(ws + o); o += 128 * 128 / 2;     // [128][128] fp16
  unsigned* deg       = (unsigned*)(ws + o); o += (size_t)N;
  unsigned* row_start = (unsigned*)(ws + o); o += (size_t)N;
  unsigned* cntA      = (unsigned*)(ws + o); o += (size_t)SB * NBUKMAX;   // 512 KB
  unsigned* blkoff    = (unsigned*)(ws + o); o += (size_t)SB * NBUKMAX;   // 512 KB
  unsigned* buktotal  = (unsigned*)(ws + o); o += NBUKMAX;
  unsigned* sd32      = (unsigned*)(ws + o); o += (size_t)EE;             // 3.4 MB
  unsigned* ebuk      = (unsigned*)(ws + o); o += (size_t)EE;             // 3.4 MB
  unsigned short* csr16 = (unsigned short*)(ws + o); o += (size_t)(EE + 1) / 2; // 1.7 MB

  const int ngrid = (N + 15) / 16;
  const int ggrid = (N + 127) / 128;

  // 1) bucket count || convW1 || convW2 || sd32 pack
  pre_kernel<<<SB + 192 + pgrid, 256, 0, stream>>>(
      ei, E, N, nbuk, epb1, cntA, sd32, W1, W1T, W2, W2T);
  // 2) per-bucket column scan
  bukoff_kernel<<<nbuk, 256, 0, stream>>>(cntA, blkoff, buktotal);
  // 3) gemm layer-1 || bucket scatter
  gemm1_scatter_kernel<<<ggrid + SB, 256, 0, stream>>>(
      E, N, nbuk, epb1, sd32, blkoff, buktotal, ebuk,
      x, W1T, as1, ad1, h, asv, adv, ggrid);
  // 4) per-bucket CSR build (deg + row_start + csr16, all bucket-local)
  csr_build_kernel<<<nbuk, 256, 0, stream>>>(
      N, nbuk, buktotal, ebuk, deg, row_start, csr16);
  // 5) aggregate layer-1 + gemm layer-2 + layer-2 dots (fused)
  agg1_gemm2_kernel<<<ngrid, 256, 0, stream>>>(
      row_start, deg, csr16, (const __half*)h, asv, adv, b1,
      W2T, as2, ad2, h2, asv2, adv2, N);
  // 6) aggregate layer-2 -> out (fp32)
  aggregate2_kernel<<<ngrid, 256, 0, stream>>>(
      row_start, deg, csr16, (const __half*)h2, asv2, adv2, b2, out, N);
}